// Round 8
// baseline (149.927 us; speedup 1.0000x reference)
//
#include <hip/hip_runtime.h>

// Problem constants (fixed by reference)
#define BATCH   16384
#define NFEAT   512
#define NTREE   64
#define NDEPTH  6
#define NLEAF   64
#define NDOUT   64
#define NLOGIT  384   // NDEPTH * NTREE

typedef float    f32x4  __attribute__((ext_vector_type(4)));
typedef _Float16 half8  __attribute__((ext_vector_type(8)));
typedef _Float16 h2v    __attribute__((ext_vector_type(2)));
typedef __fp16   fp16x2 __attribute__((ext_vector_type(2)));

union H8 { _Float16 h[8]; half8 v; uint4 q; };
union H4 { _Float16 h[4]; ushort4 u; };

// async global->LDS DMA, 16B per lane; lds dest wave-uniform base,
// HW writes lane i at base + i*16 (m97/m104 semantics).
__device__ __forceinline__ void dma16(const void* g, void* l) {
    __builtin_amdgcn_global_load_lds(
        (const __attribute__((address_space(1))) unsigned int*)g,
        (__attribute__((address_space(3))) unsigned int*)l, 16, 0, 0);
}

// ---------------------------------------------------------------------------
// prep: blocks 0..63   -> V2[t][d][l] = f16(leaf[t][l][d] / 64)
//       blocks 64..159 -> Wt[n][f-blocks, groups-of-8 XOR-swizzled by n&7]
//                         = f16(W[d][f][t]),  n = d*64+t
// ---------------------------------------------------------------------------
__global__ __launch_bounds__(256) void prep(const float* __restrict__ leaf,
                                            const float* __restrict__ W,
                                            _Float16* __restrict__ V2,
                                            _Float16* __restrict__ Wt) {
    __shared__ float T[64 * 65];
    const int tid = threadIdx.x;
    if (blockIdx.x < 64) {
        const int t = blockIdx.x;
        const float* src = leaf + (size_t)t * 4096;
        for (int j = 0; j < 4; ++j) {
            int idx = tid + 256 * j;            // 0..1023 float4s
            int l = idx >> 4, d4 = idx & 15;
            float4 v = *(const float4*)(src + l * 64 + d4 * 4);
            T[l * 65 + d4 * 4 + 0] = v.x;
            T[l * 65 + d4 * 4 + 1] = v.y;
            T[l * 65 + d4 * 4 + 2] = v.z;
            T[l * 65 + d4 * 4 + 3] = v.w;
        }
        __syncthreads();
        _Float16* dst = V2 + (size_t)t * 4096;
        for (int j = 0; j < 4; ++j) {
            int idx = tid + 256 * j;
            int d = idx >> 4, l4 = idx & 15;
            H4 u;
            u.h[0] = (_Float16)(T[(l4 * 4 + 0) * 65 + d] * 0.015625f);
            u.h[1] = (_Float16)(T[(l4 * 4 + 1) * 65 + d] * 0.015625f);
            u.h[2] = (_Float16)(T[(l4 * 4 + 2) * 65 + d] * 0.015625f);
            u.h[3] = (_Float16)(T[(l4 * 4 + 3) * 65 + d] * 0.015625f);
            *(ushort4*)(dst + d * 64 + l4 * 4) = u.u;
        }
    } else {
        const int bid = blockIdx.x - 64;        // 0..95
        const int d = bid >> 4, f0 = (bid & 15) * 32;
        for (int j = 0; j < 2; ++j) {
            int idx = tid + 256 * j;            // 0..511 float4s (32 f x 64 t)
            int f = idx >> 4, c4 = idx & 15;
            float4 v = *(const float4*)(W + ((size_t)d * 512 + f0 + f) * 64 + c4 * 4);
            T[f * 65 + c4 * 4 + 0] = v.x;
            T[f * 65 + c4 * 4 + 1] = v.y;
            T[f * 65 + c4 * 4 + 2] = v.z;
            T[f * 65 + c4 * 4 + 3] = v.w;
        }
        __syncthreads();
        const int t = tid >> 2, c8 = tid & 3;
        H8 u;
        #pragma unroll
        for (int i = 0; i < 8; ++i) u.h[i] = (_Float16)T[(c8 * 8 + i) * 65 + t];
        int g  = ((f0 & 63) >> 3) + c8;         // k-group 0..7 in this 64-block
        int gs = g ^ (t & 7);                   // (n&7) == (t&7)
        *(half8*)(Wt + ((size_t)(d * 64 + t)) * 512 + (f0 & ~63) + gs * 8) = u.v;
    }
}

// ---------------------------------------------------------------------------
// gemm1: SP[b][n] = f16(sigmoid(sum_f x[b][f]*W[f][n] + bias[n])), n=d*64+t
// m97-proven geometry: 128 rows x 64 n, BK=64, 24 KB LDS -> grid (128,6)=768
// blocks = 3/CU = 12 waves/CU. 16 MFMA/wave/iter. B via linear DMA from
// pre-swizzled Wt; A staged fp32->f16 once per element. Output B-MAJOR.
// ---------------------------------------------------------------------------
__global__ __launch_bounds__(256, 3) void gemm1(const float* __restrict__ x,
                                                const _Float16* __restrict__ Wt,
                                                const float* __restrict__ bias,
                                                _Float16* __restrict__ SP) {
    __shared__ __align__(16) char SM[24576];
    _Float16* As = (_Float16*)SM;             // [128 r][64 k swz] 16 KB
    _Float16* Bs = As + 8192;                 // [64 n][64 k swz]   8 KB
    _Float16* Tr = (_Float16*)SM;             // [128 r][72 n-pad] 18.4 KB overlay

    const int tid  = threadIdx.x;
    const int w    = tid >> 6, lane = tid & 63;
    const int quad = lane >> 4, l15 = lane & 15;
    const int wm = w & 1, wn = w >> 1;        // wave: 64 rows x 32 n
    const int bm = blockIdx.x, bn = blockIdx.y;

    const int a_row = tid & 127, a_kg = tid >> 7;   // A-stage: 2 thr/row
    const int b_r8  = lane >> 3, b_c8 = lane & 7;   // B-DMA lane mapping

    f32x4 acc[4][2];
    #pragma unroll
    for (int mt = 0; mt < 4; ++mt)
        #pragma unroll
        for (int nt = 0; nt < 2; ++nt)
            acc[mt][nt] = (f32x4){0.f, 0.f, 0.f, 0.f};

    for (int k0 = 0; k0 < NFEAT; k0 += 64) {
        // B stage: 2 DMA/wave (8 rows x 128 B each), linear (swizzle in Wt)
        #pragma unroll
        for (int i = 0; i < 2; ++i) {
            int nl = w * 16 + i * 8;
            const _Float16* g = Wt + (size_t)(bn * 64 + nl + b_r8) * 512 + k0 + b_c8 * 8;
            dma16(g, (char*)Bs + (size_t)nl * 128);
        }
        // A stage: thread covers 32 k of one row: 8 float4 loads -> 4 half8
        {
            const float* src = x + (size_t)(bm * 128 + a_row) * NFEAT + k0 + a_kg * 32;
            #pragma unroll
            for (int j = 0; j < 4; ++j) {
                float4 v0 = *(const float4*)(src + j * 8);
                float4 v1 = *(const float4*)(src + j * 8 + 4);
                H8 u;
                *(fp16x2*)&u.h[0] = __builtin_amdgcn_cvt_pkrtz(v0.x, v0.y);
                *(fp16x2*)&u.h[2] = __builtin_amdgcn_cvt_pkrtz(v0.z, v0.w);
                *(fp16x2*)&u.h[4] = __builtin_amdgcn_cvt_pkrtz(v1.x, v1.y);
                *(fp16x2*)&u.h[6] = __builtin_amdgcn_cvt_pkrtz(v1.z, v1.w);
                int g = (a_kg * 4 + j) ^ (a_row & 7);
                *(half8*)(As + a_row * 64 + g * 8) = u.v;
            }
        }
        __syncthreads();

        half8 bF[2][2];
        #pragma unroll
        for (int nt = 0; nt < 2; ++nt) {
            int n = wn * 32 + nt * 16 + l15;
            #pragma unroll
            for (int ks = 0; ks < 2; ++ks) {
                int g = (ks * 4 + quad) ^ (n & 7);
                bF[nt][ks] = *(const half8*)(Bs + n * 64 + g * 8);
            }
        }
        half8 aF[4][2];
        #pragma unroll
        for (int mt = 0; mt < 4; ++mt) {
            int r = wm * 64 + mt * 16 + l15;
            #pragma unroll
            for (int ks = 0; ks < 2; ++ks) {
                int g = (ks * 4 + quad) ^ (r & 7);
                aF[mt][ks] = *(const half8*)(As + r * 64 + g * 8);
            }
        }
        #pragma unroll
        for (int mt = 0; mt < 4; ++mt)
            #pragma unroll
            for (int nt = 0; nt < 2; ++nt)
                #pragma unroll
                for (int ks = 0; ks < 2; ++ks)
                    acc[mt][nt] = __builtin_amdgcn_mfma_f32_16x16x32_f16(
                        aF[mt][ks], bF[nt][ks], acc[mt][nt], 0, 0, 0);
        __syncthreads();
    }

    // epilogue: bias+sigmoid -> Tr[row][n] (u16 scalar LDS stores), then
    // coalesced b-major stores: SP[b][384], this block's 128-B column slice.
    #pragma unroll
    for (int nt = 0; nt < 2; ++nt) {
        int n_loc = wn * 32 + nt * 16 + l15;
        float bv = bias[bn * 64 + n_loc];
        #pragma unroll
        for (int mt = 0; mt < 4; ++mt) {
            int base = wm * 64 + mt * 16 + quad * 4;
            #pragma unroll
            for (int r = 0; r < 4; ++r) {
                float z = acc[mt][nt][r] + bv;
                Tr[(base + r) * 72 + n_loc] = (_Float16)(1.0f / (1.0f + __expf(-z)));
            }
        }
    }
    __syncthreads();
    {
        int row = tid >> 1, half = tid & 1;   // 64 B per thread
        const _Float16* s = Tr + row * 72 + half * 32;
        _Float16* d = SP + (size_t)(bm * 128 + row) * NLOGIT + bn * 64 + half * 32;
        #pragma unroll
        for (int j = 0; j < 4; ++j)
            *(uint4*)(d + j * 8) = *(const uint4*)(s + j * 8);
    }
}

// ---------------------------------------------------------------------------
// tree: out[b][d] = sum_t sum_l P[b,t,l] * V2[t][d][l]
// 512 blocks x 512 threads: 32 rows/block, 8 waves each own 8 trees ->
// 16 waves/CU (2 blocks co-resident, LDS 64.5 KB). sp staged from b-major
// SP in contiguous 768 B rows. f16 LDS reduce over 8 wave-partials.
// ---------------------------------------------------------------------------
__global__ __launch_bounds__(512, 4) void tree(const _Float16* __restrict__ SP,
                                               const _Float16* __restrict__ V2,
                                               float* __restrict__ out) {
    __shared__ _Float16 sp[32 * 392];         // [row][n pad392]  25088 B
    __shared__ _Float16 red[8 * 64 * 40];     // [wave][d][row+pad] 40960 B
    const int tid  = threadIdx.x;
    const int w = tid >> 6, lane = tid & 63;
    const int quad = lane >> 4, l15 = lane & 15;
    const int r0 = blockIdx.x * 32;

    // stage 32 rows x 768 B, fully coalesced
    #pragma unroll
    for (int j = 0; j < 3; ++j) {
        int idx = tid + 512 * j;              // 0..1535
        int row = idx / 48, c = idx % 48;
        *(uint4*)(sp + row * 392 + c * 8) =
            *(const uint4*)(SP + (size_t)(r0 + row) * NLOGIT + c * 8);
    }
    __syncthreads();

    f32x4 acc[2][4];
    #pragma unroll
    for (int mt = 0; mt < 2; ++mt)
        #pragma unroll
        for (int nt = 0; nt < 4; ++nt)
            acc[mt][nt] = (f32x4){0.f, 0.f, 0.f, 0.f};

    const _Float16 one = (_Float16)1.0f;
    for (int tl = 0; tl < 8; ++tl) {
        const int t = w * 8 + tl;
        // B frags direct from L2-hot V2
        half8 bF[4][2];
        #pragma unroll
        for (int nt = 0; nt < 4; ++nt)
            #pragma unroll
            for (int ks = 0; ks < 2; ++ks)
                bF[nt][ks] = *(const half8*)(V2 + (size_t)t * 4096 +
                                             (nt * 16 + l15) * 64 + ks * 32 + quad * 8);
        // A frags: P build (verified r5/r7 bit convention)
        half8 aF[2][2];
        #pragma unroll
        for (int mt = 0; mt < 2; ++mt) {
            int rl = mt * 16 + l15;
            const _Float16* pr = sp + rl * 392 + t;
            _Float16 p0 = pr[0 * 64], p1 = pr[1 * 64], p2 = pr[2 * 64];
            _Float16 p3 = pr[3 * 64], p4 = pr[4 * 64], p5 = pr[5 * 64];
            _Float16 q1 = (quad & 2) ? (_Float16)(one - p1) : p1;
            _Float16 q2 = (quad & 1) ? (_Float16)(one - p2) : p2;
            _Float16 pre  = q1 * q2;
            _Float16 pre0 = p0 * pre;
            _Float16 pre1 = (one - p0) * pre;
            h2v p4p = { p4, (_Float16)(one - p4) };
            h2v p5p = { p5, (_Float16)(one - p5) };
            h2v t34a = (h2v){ p3, p3 } * p4p;
            _Float16 p3b = one - p3;
            h2v t34b = (h2v){ p3b, p3b } * p4p;
            h2v w0 = (h2v){ t34a[0], t34a[0] } * p5p;
            h2v w1 = (h2v){ t34a[1], t34a[1] } * p5p;
            h2v w2 = (h2v){ t34b[0], t34b[0] } * p5p;
            h2v w3 = (h2v){ t34b[1], t34b[1] } * p5p;
            h2v P0 = { pre0, pre0 }, P1 = { pre1, pre1 };
            H8 a0, a1;
            *(h2v*)&a0.h[0] = P0 * w0; *(h2v*)&a0.h[2] = P0 * w1;
            *(h2v*)&a0.h[4] = P0 * w2; *(h2v*)&a0.h[6] = P0 * w3;
            *(h2v*)&a1.h[0] = P1 * w0; *(h2v*)&a1.h[2] = P1 * w1;
            *(h2v*)&a1.h[4] = P1 * w2; *(h2v*)&a1.h[6] = P1 * w3;
            aF[mt][0] = a0.v;
            aF[mt][1] = a1.v;
        }
        #pragma unroll
        for (int mt = 0; mt < 2; ++mt)
            #pragma unroll
            for (int nt = 0; nt < 4; ++nt)
                #pragma unroll
                for (int ks = 0; ks < 2; ++ks)
                    acc[mt][nt] = __builtin_amdgcn_mfma_f32_16x16x32_f16(
                        aF[mt][ks], bF[nt][ks], acc[mt][nt], 0, 0, 0);
    }

    // per-wave f16 partials -> LDS
    #pragma unroll
    for (int mt = 0; mt < 2; ++mt)
        #pragma unroll
        for (int nt = 0; nt < 4; ++nt) {
            H4 h;
            #pragma unroll
            for (int r = 0; r < 4; ++r) h.h[r] = (_Float16)acc[mt][nt][r];
            *(ushort4*)(red + (w * 64 + nt * 16 + l15) * 40 + mt * 16 + quad * 4) = h.u;
        }
    __syncthreads();

    // reduce 8 partials, coalesced float4 stores
    {
        int bl = tid >> 4, d4 = (tid & 15) * 4;   // row 0..31, d 0..60
        float s[4] = {0.f, 0.f, 0.f, 0.f};
        #pragma unroll
        for (int ww = 0; ww < 8; ++ww)
            #pragma unroll
            for (int i = 0; i < 4; ++i)
                s[i] += (float)red[(ww * 64 + d4 + i) * 40 + bl];
        float4 o = { s[0], s[1], s[2], s[3] };
        *(float4*)(out + (size_t)(r0 + bl) * NDOUT + d4) = o;
    }
}

// ---------------------------------------------------------------------------
extern "C" void kernel_launch(void* const* d_in, const int* in_sizes, int n_in,
                              void* d_out, int out_size, void* d_ws, size_t ws_size,
                              hipStream_t stream) {
    const float* x    = (const float*)d_in[0];  // (16384, 512)
    const float* W    = (const float*)d_in[1];  // (6, 512, 64)
    const float* bias = (const float*)d_in[2];  // (6, 64) flat = 384
    const float* leaf = (const float*)d_in[3];  // (64, 64, 64)
    float* out = (float*)d_out;                 // (16384, 64)

    // ws: SP f16 [16384][384] b-major (12.58 MB) | V2 f16 512 KB | Wt f16 384 KB
    _Float16* SP = (_Float16*)d_ws;
    _Float16* V2 = SP + (size_t)BATCH * NLOGIT;
    _Float16* Wt = V2 + (size_t)NTREE * NLEAF * NDOUT;

    prep<<<160, 256, 0, stream>>>(leaf, W, V2, Wt);
    gemm1<<<dim3(BATCH / 128, NDEPTH), 256, 0, stream>>>(x, Wt, bias, SP);
    tree<<<BATCH / 32, 512, 0, stream>>>(SP, V2, out);
}